// Round 9
// baseline (523.778 us; speedup 1.0000x reference)
//
#include <hip/hip_runtime.h>
#include <math.h>

#define PW 32
#define PL 64
#define PK 512
#define PN 64
// vectors total: PW*PL*PK = 1,048,576

typedef int   v4i __attribute__((ext_vector_type(4)));
typedef float v4f __attribute__((ext_vector_type(4)));   // clang vector: OK for
                                                         // __builtin_nontemporal_*

// ---------------- Kernel 1: energies via exact-int i8 MFMA ----------------
// E = s^T Q s, s in {0,1}. R = llrint(Q * 2^28) exact int64 (|R|<2^30.3 for
// |Q|<8.5); R split into 4 signed base-256 i8 digits. Per digit:
// C[j,v] = sum_i digit(R[i,j]) * s_i via v_mfma_i32_16x16x64_i8 (i32 exact).
// Epilogue selects sum_j s_j C[j,v]; digits recombined in int64, scaled
// 2^-28. Rounding RMS ~1.1e-9/entry; with dbeta~0.03 the delta err RMS ~5e-9
// -> expected mask flips ~0.003 over 1M (half are exp(delta)>=1, immune).
//
// Structure: 32 vectors per iteration (two B tiles share each A fragment
// load -> ds_read_b128 + s_nop cost halved per vector).
//
// Layouts (C/D HW-verified; A/B standard):
//   A[m][k]: m = lane&15 (=j_local), k = (lane>>4)*16 + b, b=byte 0..15
//   B[k][n]: n = lane&15 (=v_local), k = (lane>>4)*16 + b
//   C[m][n]: n = lane&15, m = (lane>>4)*4 + reg

constexpr int ITERS_PER_WAVE = 4;   // 32 vectors/iter -> 128 vectors/wave

__global__ __launch_bounds__(256) void energies_kernel(
    const float* __restrict__ states, const float* __restrict__ Q,
    float* __restrict__ e_out, double* __restrict__ e64)
{
    __shared__ alignas(16) signed char Afrag[16 * 64 * 16];  // [k*4+jt][lane][b]

    const int tid  = threadIdx.x;
    const int lane = tid & 63;
    const int wv   = tid >> 6;
    const int w    = blockIdx.x >> 6;        // 64 blocks per w
    const int blk  = blockIdx.x & 63;

    // ---- build digit fragments of Q[w] in LDS (once per block) ----
    const float* Qw = Q + w * PN * PN;
    for (int e = tid; e < PN * PN; e += 256) {
        const int i = e >> 6, j = e & 63;
        long long R = llrint((double)Qw[e] * 268435456.0);   // * 2^28
        const int frag_lane = ((i >> 4) << 4) | (j & 15);
        const int jt = j >> 4;
        const int b  = i & 15;
#pragma unroll
        for (int k = 0; k < 4; ++k) {
            const signed char d = (signed char)(R & 0xFF);
            R = (R - d) >> 8;
            Afrag[((k * 4 + jt) * 64 + frag_lane) * 16 + b] = d;
        }
    }
    __syncthreads();

    const v4i* Af = (const v4i*)Afrag;       // [(k*4+jt)*64 + lane]

    const long vw_base = (long)w * (PL * PK)
                       + (long)(blk * 4 + wv) * (32 * ITERS_PER_WAVE);

    for (int t = 0; t < ITERS_PER_WAVE; ++t) {
        const long vbase = vw_base + (long)t * 32;
        const float* sp = states + vbase * PN + lane;

        // ---- 32 ballots -> lane keeps masks of vectors (lane&15, +16) ----
        unsigned long long mkA = 0, mkB = 0;
#pragma unroll
        for (int v = 0; v < 16; ++v) {
            const float sA = sp[v * PN];
            const float sB = sp[(v + 16) * PN];
            const unsigned long long mA = __ballot(sA != 0.0f);
            const unsigned long long mB = __ballot(sB != 0.0f);
            const bool sel = (lane & 15) == v;
            mkA = sel ? mA : mkA;
            mkB = sel ? mB : mkB;
        }

        // ---- B fragments: bytes b = s_{i=(lane>>4)*16+b} of vector ----
        const int sh = (lane >> 4) * 16;
        const unsigned int bA = (unsigned int)(mkA >> sh) & 0xFFFFu;
        const unsigned int bB = (unsigned int)(mkB >> sh) & 0xFFFFu;
        v4i BA, BB;
#pragma unroll
        for (int q = 0; q < 4; ++q) {
            BA[q] = (int)((((bA >> (4 * q)) & 0xFu) * 0x00204081u) & 0x01010101u);
            BB[q] = (int)((((bB >> (4 * q)) & 0xFu) * 0x00204081u) & 0x01010101u);
        }

        // ---- epilogue row-select bits: j = jt*16 + (lane>>4)*4 + reg ----
        int selA[4], selB[4];
#pragma unroll
        for (int jt = 0; jt < 4; ++jt) {
            selA[jt] = (int)((mkA >> (jt * 16 + ((lane >> 4) * 4))) & 0xF);
            selB[jt] = (int)((mkB >> (jt * 16 + ((lane >> 4) * 4))) & 0xF);
        }

        long long accA = 0, accB = 0;
#pragma unroll
        for (int k = 0; k < 4; ++k) {
            v4i A0 = Af[(k * 4 + 0) * 64 + lane];
            v4i A1 = Af[(k * 4 + 1) * 64 + lane];
            v4i A2 = Af[(k * 4 + 2) * 64 + lane];
            v4i A3 = Af[(k * 4 + 3) * 64 + lane];
            v4i CA0 = {0,0,0,0}, CA1 = {0,0,0,0}, CA2 = {0,0,0,0}, CA3 = {0,0,0,0};
            v4i CB0 = {0,0,0,0}, CB1 = {0,0,0,0}, CB2 = {0,0,0,0}, CB3 = {0,0,0,0};
            asm("s_nop 1\n\t"
                "v_mfma_i32_16x16x64_i8 %0, %8, %12, %0\n\t"
                "v_mfma_i32_16x16x64_i8 %4, %8, %13, %4\n\t"
                "v_mfma_i32_16x16x64_i8 %1, %9, %12, %1\n\t"
                "v_mfma_i32_16x16x64_i8 %5, %9, %13, %5\n\t"
                "v_mfma_i32_16x16x64_i8 %2, %10, %12, %2\n\t"
                "v_mfma_i32_16x16x64_i8 %6, %10, %13, %6\n\t"
                "v_mfma_i32_16x16x64_i8 %3, %11, %12, %3\n\t"
                "v_mfma_i32_16x16x64_i8 %7, %11, %13, %7\n\t"
                "s_nop 7\n\t"
                "s_nop 7"
                : "+v"(CA0), "+v"(CA1), "+v"(CA2), "+v"(CA3),
                  "+v"(CB0), "+v"(CB1), "+v"(CB2), "+v"(CB3)
                : "v"(A0), "v"(A1), "v"(A2), "v"(A3), "v"(BA), "v"(BB));
            int akA = 0, akB = 0;
#pragma unroll
            for (int r = 0; r < 4; ++r) {
                akA += ((selA[0] >> r) & 1) * CA0[r];
                akA += ((selA[1] >> r) & 1) * CA1[r];
                akA += ((selA[2] >> r) & 1) * CA2[r];
                akA += ((selA[3] >> r) & 1) * CA3[r];
                akB += ((selB[0] >> r) & 1) * CB0[r];
                akB += ((selB[1] >> r) & 1) * CB1[r];
                akB += ((selB[2] >> r) & 1) * CB2[r];
                akB += ((selB[3] >> r) & 1) * CB3[r];
            }
            accA += (long long)akA << (8 * k);
            accB += (long long)akB << (8 * k);
        }

        // ---- reduce the 4 lane-groups holding the same v = lane&15 ----
        accA += __shfl_xor(accA, 16, 64);
        accA += __shfl_xor(accA, 32, 64);
        accB += __shfl_xor(accB, 16, 64);
        accB += __shfl_xor(accB, 32, 64);

        if (lane < 16) {
            const double eA = (double)accA * 0x1p-28;
            const double eB = (double)accB * 0x1p-28;
            e64[vbase + lane]        = eA;
            e_out[vbase + lane]      = (float)eA;
            e64[vbase + 16 + lane]   = eB;
            e_out[vbase + 16 + lane] = (float)eB;
        }
    }
}

// ---------------- Kernel 2: exchange masks ----------------
__global__ __launch_bounds__(256) void mask_kernel(
    const double* __restrict__ e64, const float* __restrict__ beta,
    const float* __restrict__ u, unsigned char* __restrict__ mask)
{
    const int idx = blockIdx.x * blockDim.x + threadIdx.x;
    if (idx >= PW * (PL - 1) * PK) return;
    const int k = idx % PK;
    const int m = (idx / PK) % (PL - 1);
    const int w = idx / (PK * (PL - 1));
    const long e1 = ((long)w * PL + m) * PK + k;
    const double db = (double)beta[m + 1] - (double)beta[m];
    const double delta = (e64[e1 + PK] - e64[e1]) * db;
    mask[idx] = ((double)u[idx] < exp(delta)) ? 1 : 0;
}

// ---------------- Kernel 3: masked replica swap ----------------
// new[w,0]   = mask[w,0]   ? s[w,1]   : s[w,0]
// new[w,l>0] = mask[w,l-1] ? s[w,l-1] : s[w,l]
// Nontemporal stores (output never re-read; skip L2 write-allocate) using
// clang ext-vector v4f — HIP float4 is a class type the builtin rejects.
__global__ __launch_bounds__(256) void swap_kernel(
    const float* __restrict__ states, const unsigned char* __restrict__ mask,
    float* __restrict__ out)
{
    const long rowBase = (long)blockIdx.x * 32;     // (w*L + l)*K + k0
    const int w  = (int)(rowBase >> 15);            // / (L*K)
    const int l  = (int)((rowBase >> 9) & 63);
    const int k0 = (int)(rowBase & 511);

    const int tid = threadIdx.x;
    const int r  = tid >> 3;                        // row within block, 0..31
    const int j4 = tid & 7;                         // float4 index 0..7 (x2)
    const int k  = k0 + r;

    const int ml = (l == 0) ? 0 : (l - 1);
    const unsigned char mk = mask[((long)w * (PL - 1) + ml) * PK + k];
    int sl;
    if (l == 0) sl = mk ? 1 : 0;
    else        sl = mk ? (l - 1) : l;

    const v4f* srcp = (const v4f*)(states + (((long)w * PL + sl) * PK + k) * PN);
    v4f*       dstp = (v4f*)(out + (rowBase + r) * PN);
    __builtin_nontemporal_store(srcp[j4],     &dstp[j4]);
    __builtin_nontemporal_store(srcp[j4 + 8], &dstp[j4 + 8]);
}

extern "C" void kernel_launch(void* const* d_in, const int* in_sizes, int n_in,
                              void* d_out, int out_size, void* d_ws, size_t ws_size,
                              hipStream_t stream) {
    const float* states = (const float*)d_in[0];
    const float* Q      = (const float*)d_in[1];
    const float* beta   = (const float*)d_in[2];
    const float* u      = (const float*)d_in[3];

    float* e_out      = (float*)d_out;
    float* new_states = (float*)d_out + (long)PW * PL * PK;

    double* e64 = (double*)d_ws;
    unsigned char* mask = (unsigned char*)d_ws + sizeof(double) * (long)PW * PL * PK;

    // K1: 2048 blocks; block = 4 waves; wave = 4 iters x 32 vectors
    //     -> 2048 * 4 * 128 = 1,048,576 vectors
    energies_kernel<<<2048, 256, 0, stream>>>(states, Q, e_out, e64);

    const int nmask = PW * (PL - 1) * PK;
    mask_kernel<<<(nmask + 255) / 256, 256, 0, stream>>>(e64, beta, u, mask);

    // K3: 1,048,576 rows / 32 per block = 32768 blocks
    swap_kernel<<<32768, 256, 0, stream>>>(states, mask, new_states);
}